// Round 8
// baseline (173.898 us; speedup 1.0000x reference)
//
#include <hip/hip_runtime.h>

// Capsule EM routing, fully fused: votes recomputed in registers each pass.
// B=32, H=W=8, I=32 -> N=2048, O=64, P=16, routings=3.
//
// R8: kill the L1 line-lookup wall. Invariant across R0-R7: accum ~42-50us
// regardless of occupancy/staging => shared per-CU pipe. Culprit: wmat
// loads. Lane o reads wmat[(i*64+o)*16] -> adjacent lanes 64B apart; each
// dwordx4 touches 64 cache lines using 16B of each, and the 4 loads/iter
// re-request the same 64 lines: 256 L1 tag-lookups/(wave,iter) @1/cyc
// = 27.3us/CU/pass == the wall. Fix: transpose w once into ws as
// w_t[i][p][o]; inner loop reads lane-contiguous dwords (16 instr x 4
// fully-used lines = 64 lookups, 4x less). Rest is the R7-proven structure:
// 512 WGs x 1024 thd, scalar (SMEM-pipe) pose/act loads, stats fused into
// the next accum (double-buffered partials), non-atomic barrier-sequenced
// LDS reduce, plain launch_bounds, no unroll pragmas on the outer loop,
// no atomics, no memset, no cooperative launch (R6 crash).

#define NB 32
#define NN 2048
#define NO 64
#define NP 16
#define EPSF 1e-7f

#define SPB 4                 // sites per block (one per 4-wave group)
#define NCHUNK 16             // chunks per batch sample
#define BLK_N (SPB * 32)      // 128 n per block

// partial/stats layout per batch: [slot][o], slots 0..15 = sum rr'*v,
// 16..31 = sum rr'*v^2, 32 = rps (stats form: mean / 0.5/var / zz_base).
#define ACC_SLOTS 33
#define ACC_PER_B (ACC_SLOTS * NO)              // 2112 floats
#define PART_PER_BATCH (NCHUNK * ACC_PER_B)     // 33792 floats
#define PART_TOTAL (NB * PART_PER_BATCH)        // 1,081,344 floats
#define WT_FLOATS (32 * 16 * 64)                // 32768

__global__ __launch_bounds__(1024) void transpose_w(
    const float* __restrict__ wmat,  // [32][64][16]
    float* __restrict__ wt)          // [32][16][64]
{
    const int idx = blockIdx.x * 1024 + threadIdx.x;  // 0..32767
    const int i = idx >> 10;
    const int p = (idx >> 6) & 15;
    const int o = idx & 63;
    wt[idx] = wmat[((size_t)i * 64 + o) * 16 + p];   // write coalesced
}

// non-atomic cross-wave reduce (barrier-sequenced) + coalesced partial store
__device__ __forceinline__ void reduce_store(
    float buf[SPB][ACC_PER_B], int wvin, int grp, int o, int tid,
    float accR, const float* acc1, const float* acc2, float* __restrict__ pc)
{
    if (wvin == 3) {
        float* r = buf[grp];
        r[32 * 64 + o] = accR;
        #pragma unroll
        for (int p = 0; p < 16; p++) r[p * 64 + o] = acc1[p];
        #pragma unroll
        for (int p = 0; p < 16; p++) r[(16 + p) * 64 + o] = acc2[p];
    }
    __syncthreads();
    for (int round = 2; round >= 0; --round) {
        if (wvin == round) {
            float* r = buf[grp];
            r[32 * 64 + o] += accR;
            #pragma unroll
            for (int p = 0; p < 16; p++) r[p * 64 + o] += acc1[p];
            #pragma unroll
            for (int p = 0; p < 16; p++) r[(16 + p) * 64 + o] += acc2[p];
        }
        __syncthreads();
    }
    for (int j = tid; j < ACC_PER_B; j += 1024)
        pc[j] = buf[0][j] + buf[1][j] + buf[2][j] + buf[3][j];
}

template <bool FIRST>
__global__ __launch_bounds__(1024) void accum_kernel(
    const float* __restrict__ pose,      // [B][N][16]
    const float* __restrict__ act,       // [B][N]
    const float* __restrict__ wt,        // [32][16][64] transposed weights
    const float* __restrict__ beta_v,    // [64]
    const float* __restrict__ beta_a,    // [64]
    const float* __restrict__ part_prev, // [B][16][33*64] or null (FIRST)
    float* __restrict__ part_out,        // [B][16][33*64]
    float inv_temp)                      // for the inline stats (prev iter)
{
    __shared__ float buf[SPB][ACC_PER_B];    // 33.8 KB

    const int b = blockIdx.y;
    const int chunk = blockIdx.x;            // 0..15
    const int n0 = chunk * BLK_N;
    const int tid = threadIdx.x;
    const int wv = tid >> 6, grp = wv >> 2, wvin = wv & 3, o = tid & 63;

    float m[16], i2v[16], zzb = 0.f;
    if (!FIRST) {
        // ---- inline stats of the previous pass (redundant per block) ----
        float* sb = buf[0];
        {
            const float4* p4 = (const float4*)(part_prev + (size_t)b * PART_PER_BATCH);
            float4* a4 = (float4*)sb;
            for (int j = tid; j < ACC_PER_B / 4; j += 1024) {
                float4 s = make_float4(0.f, 0.f, 0.f, 0.f);
                #pragma unroll
                for (int c = 0; c < NCHUNK; c++) {
                    float4 vv = p4[c * (ACC_PER_B / 4) + j];
                    s.x += vv.x; s.y += vv.y; s.z += vv.z; s.w += vv.w;
                }
                a4[j] = s;
            }
        }
        __syncthreads();
        if (tid < 64) {   // one wave does the per-o stats math, in place
            float rps = sb[32 * 64 + o];
            float mm[16], var[16];
            float logsum = 0.f;
            #pragma unroll
            for (int p = 0; p < 16; p++) {
                float s1 = sb[p * 64 + o];
                float s2 = sb[(16 + p) * 64 + o];
                float mv = s1 / rps;
                float vv = fmaxf(s2 / rps - mv * mv, 0.f);
                mm[p] = mv;
                var[p] = vv;
                logsum += __logf(sqrtf(vv) + EPSF);
            }
            float cost = rps * (16.0f * beta_v[o] + logsum);
            float cm = cost;
            #pragma unroll
            for (int s = 32; s > 0; s >>= 1) cm += __shfl_xor(cm, s, 64);
            cm *= (1.0f / 64.0f);
            float dd = cost - cm;
            float cs = dd * dd;
            #pragma unroll
            for (int s = 32; s > 0; s >>= 1) cs += __shfl_xor(cs, s, 64);
            cs = sqrtf(cs * (1.0f / 64.0f));
            float x = inv_temp * (beta_a[o] + (cm - cost) / (cs + EPSF));
            float oa = 1.0f / (1.0f + __expf(-x));
            #pragma unroll
            for (int p = 0; p < 16; p++) sb[p * 64 + o] = mm[p];
            #pragma unroll
            for (int p = 0; p < 16; p++) sb[(16 + p) * 64 + o] = 0.5f / var[p];
            sb[32 * 64 + o] = __logf(oa + EPSF) - logsum;
        }
        __syncthreads();
        #pragma unroll
        for (int p = 0; p < 16; p++) m[p] = sb[p * 64 + o];
        #pragma unroll
        for (int p = 0; p < 16; p++) i2v[p] = sb[(16 + p) * 64 + o];
        zzb = sb[32 * 64 + o];
        __syncthreads();   // everyone done reading before buf reuse in reduce
    }

    // ---- accumulation pass ----
    // pose/act: wave-uniform SCALAR loads (SMEM pipe). w: lane-contiguous
    // dword loads from the transposed copy (4 fully-used lines per instr).
    const float* pose_b = pose + ((size_t)b * NN + n0) * 16;
    const float* act_b  = act + (size_t)b * NN + n0;
    const int site = chunk * SPB + grp;      // 0..63
    const float c0 = ((site >> 3) + 0.5f) * 0.125f;
    const float c1 = ((site & 7) + 0.5f) * 0.125f;

    float accR = 0.f, acc1[16], acc2[16];
    #pragma unroll
    for (int p = 0; p < 16; p++) { acc1[p] = 0.f; acc2[p] = 0.f; }

    for (int ii = 0; ii < 8; ii++) {
        const int i = wvin * 8 + ii;         // capsule index 0..31
        const int nl = __builtin_amdgcn_readfirstlane(grp * 32 + i);
        const float4* pr4 = (const float4*)(pose_b + (size_t)nl * 16);
        const float av = act_b[nl];

        // w[b*4+c] = w_t[i][(b*4+c)*64 + o]  -- coalesced across lanes
        const float* wti = wt + (size_t)i * 1024 + o;
        float w[16];
        #pragma unroll
        for (int p = 0; p < 16; p++) w[p] = wti[p * 64];

        float v[16];
        #pragma unroll
        for (int a = 0; a < 4; a++) {
            float4 pa = pr4[a];
            #pragma unroll
            for (int c = 0; c < 4; c++) {
                v[a * 4 + c] = pa.x * w[c] + pa.y * w[4 + c] +
                               pa.z * w[8 + c] + pa.w * w[12 + c];
            }
        }
        v[0] += c0;
        v[1] += c1;

        float rr;
        if (FIRST) {
            rr = 1.0f / 64.0f;
        } else {
            float d = zzb;
            #pragma unroll
            for (int p = 0; p < 16; p++) {
                float t = v[p] - m[p];
                d -= t * t * i2v[p];
            }
            // softmax over the 64 o-lanes
            float mx = d;
            #pragma unroll
            for (int s = 32; s > 0; s >>= 1) mx = fmaxf(mx, __shfl_xor(mx, s, 64));
            float e = __expf(d - mx);
            float sum = e;
            #pragma unroll
            for (int s = 32; s > 0; s >>= 1) sum += __shfl_xor(sum, s, 64);
            rr = e / sum;
        }
        float rp = rr * av;
        accR += rp;
        #pragma unroll
        for (int p = 0; p < 16; p++) {
            acc1[p] += rp * v[p];
            acc2[p] += rp * v[p] * v[p];
        }
    }

    float* pc = part_out + ((size_t)b * NCHUNK + chunk) * ACC_PER_B;
    reduce_store(buf, wvin, grp, o, tid, accR, acc1, acc2, pc);
}

__global__ __launch_bounds__(256) void stats_final(
    const float* __restrict__ part,    // [B][16][33*64]
    const float* __restrict__ beta_v,  // [64]
    const float* __restrict__ beta_a,  // [64]
    float* __restrict__ out,
    float inv_temp)
{
    __shared__ float acc_s[ACC_PER_B];

    const int b = blockIdx.x;
    const int tid = threadIdx.x;

    {
        const float4* p4 = (const float4*)(part + (size_t)b * PART_PER_BATCH);
        float4* a4 = (float4*)acc_s;
        for (int j = tid; j < ACC_PER_B / 4; j += 256) {
            float4 s = make_float4(0.f, 0.f, 0.f, 0.f);
            #pragma unroll
            for (int c = 0; c < NCHUNK; c++) {
                float4 vv = p4[c * (ACC_PER_B / 4) + j];
                s.x += vv.x; s.y += vv.y; s.z += vv.z; s.w += vv.w;
            }
            a4[j] = s;
        }
    }
    __syncthreads();

    if (tid < 64) {
        const int o = tid;
        float rps = acc_s[32 * 64 + o];
        float m[16];
        float logsum = 0.f;
        #pragma unroll
        for (int p = 0; p < 16; p++) {
            float s1 = acc_s[p * 64 + o];
            float s2 = acc_s[(16 + p) * 64 + o];
            float mm = s1 / rps;
            float vv = fmaxf(s2 / rps - mm * mm, 0.f);
            m[p] = mm;
            logsum += __logf(sqrtf(vv) + EPSF);
        }
        float cost = rps * (16.0f * beta_v[o] + logsum);

        float cm = cost;
        #pragma unroll
        for (int s = 32; s > 0; s >>= 1) cm += __shfl_xor(cm, s, 64);
        cm *= (1.0f / 64.0f);
        float dd = cost - cm;
        float cs = dd * dd;
        #pragma unroll
        for (int s = 32; s > 0; s >>= 1) cs += __shfl_xor(cs, s, 64);
        cs = sqrtf(cs * (1.0f / 64.0f));

        float x = inv_temp * (beta_a[o] + (cm - cost) / (cs + EPSF));
        float oa = 1.0f / (1.0f + __expf(-x));

        float* op = out + ((size_t)b * 64 + o) * 16;
        #pragma unroll
        for (int p = 0; p < 16; p++) op[p] = m[p];
        out[(size_t)NB * NO * NP + (size_t)b * 64 + o] = oa;
    }
}

extern "C" void kernel_launch(void* const* d_in, const int* in_sizes, int n_in,
                              void* d_out, int out_size, void* d_ws, size_t ws_size,
                              hipStream_t stream) {
    const float* pose   = (const float*)d_in[0];  // (32,8,8,32,4,4)
    const float* act    = (const float*)d_in[1];  // (32,8,8,32)
    const float* wmat   = (const float*)d_in[2];  // (32,64,4,4)
    const float* beta_v = (const float*)d_in[3];  // (1,64)
    const float* beta_a = (const float*)d_in[4];  // (1,64)
    float* out = (float*)d_out;
    float* ws = (float*)d_ws;

    float* pA = ws;                            // 1,081,344 floats
    float* pB = ws + (size_t)PART_TOTAL;       // 1,081,344 floats
    float* wt = pB + (size_t)PART_TOTAL;       //    32,768 floats
    // every read slot is written by a preceding launch -> no memset

    transpose_w<<<WT_FLOATS / 1024, 1024, 0, stream>>>(wmat, wt);

    dim3 grid(NCHUNK, NB);
    accum_kernel<true ><<<grid, 1024, 0, stream>>>(pose, act, wt, beta_v, beta_a,
                                                   nullptr, pA, 0.0f);
    accum_kernel<false><<<grid, 1024, 0, stream>>>(pose, act, wt, beta_v, beta_a,
                                                   pA, pB, 1.0f);
    accum_kernel<false><<<grid, 1024, 0, stream>>>(pose, act, wt, beta_v, beta_a,
                                                   pB, pA, 2.0f);
    stats_final<<<NB, 256, 0, stream>>>(pA, beta_v, beta_a, out, 3.0f);
}